// Round 11
// baseline (2215.130 us; speedup 1.0000x reference)
//
#include <hip/hip_runtime.h>
#include <hip/hip_bf16.h>
#include <math.h>

// ---------------------------------------------------------------------------
// KokoroModel: LSTM encoder (bidir) -> cross-attn -> LSTM decoder.
// B=16, T_txt=256, T_mel=400, H=512, NH=8, HD=64, V=256, M=80.
// Float inputs/outputs are FLOAT32 on device; indices int32.
// Internal compute: bf16 MFMA with f32 accumulation.
// Activation matrices are stored row-major with row index r = t*16 + b.
//
// LSTM recurrences: persistent kernels, 8 blocks x 256 thr per direction;
// h exchanged through TAGGED words ((step<<16)|bf16), parity double-buffered.
// CONVERGED configuration (r0-r10). Closed axes, do not revisit:
//  - publish: __hip_atomic_store(...,AGENT) 2x u64      [ONLY proven-fast]
//  - poll:    inline-asm global_load_dwordx4 sc1 + vmcnt(0)  [ONLY proven]
//  - sc0 loads / volatile stores / asm sc1 stores: NOT visible (r2,r4 hang)
//  - never exit a poll loop with loads in flight (r5 NaN: VGPR reuse)
//  - sentinel indirection (r6 -53%), atomic-RMW publish (r7 -32%): regress
//  - weight preload wf[4][16] (~256 regs, unified VGPR/AGPR file) is
//    LOAD-BEARING: in-loop Whh loads can't be hoisted past the poll's
//    "memory" clobbers (r8, 4.6x regress); 512-thr blocks cap regs at 256
//    -> wf spills to scratch (r9, 2.7x regress, VGPR_Count 128).
// Step time ~2.5us = compute (~1200cy) + MALL publish-to-visible (~3600cy).
// THIS REVISION (single variable): s_sleep 16 back-off before the first
// poll round of each step — publishes ack during the sleep (off-path) and
// ~2 hopeless early poll rounds' MALL traffic disappear. Encoder (16
// pollers) measured 1.56x slower/step than decoder (8) at identical work:
// the only direct contention evidence; this tests it at zero risk.
// ---------------------------------------------------------------------------

typedef short s16;
typedef __attribute__((ext_vector_type(8))) short bf16x8;
typedef __attribute__((ext_vector_type(4))) short s16x4;
typedef __attribute__((ext_vector_type(4))) float f32x4;
typedef __attribute__((ext_vector_type(4))) unsigned u32x4;

#define DEV static __device__ __forceinline__

DEV float b2f(s16 v) {
    unsigned u = ((unsigned)(unsigned short)v) << 16;
    return __builtin_bit_cast(float, u);
}
DEV s16 f2b(float f) {
    unsigned u = __builtin_bit_cast(unsigned, f);
    return (s16)((u + 0x7fffu + ((u >> 16) & 1u)) >> 16);
}

// fast device transcendentals (v_exp_f32 / v_rcp_f32); |err| ~1e-7, far
// below the bf16 quantization already present in this pipeline.
DEV float sigm_f(float x) {
    return __builtin_amdgcn_rcpf(1.0f + __builtin_amdgcn_exp2f(-1.4426950408889634f * x));
}
DEV float tanh_f(float x) {
    float e = __builtin_amdgcn_exp2f(2.8853900817779268f * x);
    return 1.0f - 2.0f * __builtin_amdgcn_rcpf(e + 1.0f);
}

static const bf16x8 BZERO = {0,0,0,0,0,0,0,0};

// ---------------------------------------------------------------------------
// Fused f32 -> bf16 conversion for all 12 weight tensors (one launch).
// ---------------------------------------------------------------------------
struct CvtSeg { const float* src; s16* dst; int n4; };
struct CvtArgs { CvtSeg seg[12]; int blk_off[12]; };

__global__ __launch_bounds__(256) void cvt_all_k(CvtArgs a)
{
    int blk = blockIdx.x;
    int si = 0;
    #pragma unroll
    for (int k = 1; k < 12; k++) si += (blk >= a.blk_off[k]) ? 1 : 0;
    int i = (blk - a.blk_off[si]) * 256 + threadIdx.x;
    if (i >= a.seg[si].n4) return;
    float4 v = ((const float4*)a.seg[si].src)[i];
    s16x4 o = { f2b(v.x), f2b(v.y), f2b(v.z), f2b(v.w) };
    *(s16x4*)(a.seg[si].dst + 4 * (size_t)i) = o;
}

// ---------------------------------------------------------------------------
// Generic GEMM: C[M][N] = A[M][K](bf16) @ W[N][K]^T + b1 + b2.
// Block: 256 thr = 4 waves in 2x2; block tile 128(M) x 128(N);
// wave tile 64x64 = 4x4 MFMA subtiles; per K-step: 8 loads -> 16 MFMA.
// ---------------------------------------------------------------------------
__global__ __launch_bounds__(256) void gemm_k(
    const s16* __restrict__ A, int lda,
    const s16* __restrict__ W, int ldw,
    const float* __restrict__ b1, const float* __restrict__ b2,
    s16* __restrict__ C, float* __restrict__ Cf, int ldc,
    int M, int N, int K, int perm_tmel)
{
    int tid = threadIdx.x;
    int w = tid >> 6, l = tid & 63;
    int lr = l & 15, lk = l >> 4;
    int m0 = blockIdx.x * 128 + (w >> 1) * 64;
    int n0 = blockIdx.y * 128 + (w & 1) * 64;

    f32x4 acc[4][4];
    #pragma unroll
    for (int i = 0; i < 4; i++)
        #pragma unroll
        for (int j = 0; j < 4; j++) acc[i][j] = (f32x4){0.f, 0.f, 0.f, 0.f};

    for (int kk = 0; kk < K; kk += 32) {
        int kb = kk + lk * 8;
        bool kok = (kb + 8) <= K;
        bf16x8 av[4], bv[4];
        #pragma unroll
        for (int mi = 0; mi < 4; mi++) {
            int arow = m0 + mi * 16 + lr;
            av[mi] = (arow < M && kok) ? *(const bf16x8*)(A + (size_t)arow * lda + kb) : BZERO;
        }
        #pragma unroll
        for (int ni = 0; ni < 4; ni++) {
            int wrow = n0 + ni * 16 + lr;
            bv[ni] = (wrow < N && kok) ? *(const bf16x8*)(W + (size_t)wrow * ldw + kb) : BZERO;
        }
        #pragma unroll
        for (int mi = 0; mi < 4; mi++)
            #pragma unroll
            for (int ni = 0; ni < 4; ni++)
                acc[mi][ni] = __builtin_amdgcn_mfma_f32_16x16x32_bf16(av[mi], bv[ni], acc[mi][ni], 0, 0, 0);
    }

    #pragma unroll
    for (int ni = 0; ni < 4; ni++) {
        int col = n0 + ni * 16 + lr;
        if (col >= N) continue;
        float bias = 0.f;
        if (b1) bias += b1[col];
        if (b2) bias += b2[col];
        #pragma unroll
        for (int mi = 0; mi < 4; mi++) {
            #pragma unroll
            for (int r = 0; r < 4; r++) {
                int row = m0 + mi * 16 + lk * 4 + r;
                if (row >= M) continue;
                float v = acc[mi][ni][r] + bias;
                size_t oidx;
                if (perm_tmel) {
                    int bb = row & 15, t = row >> 4;
                    oidx = ((size_t)bb * perm_tmel + t) * ldc + col;
                } else {
                    oidx = (size_t)row * ldc + col;
                }
                if (Cf) Cf[oidx] = v;
                else    C[oidx] = f2b(v);
            }
        }
    }
}

// ---------------------------------------------------------------------------
// Embedding: x[(t*16+b)*512 + h] = emb_b[idx[b][t]*512 + h]  (bf16 gather)
// ---------------------------------------------------------------------------
__global__ __launch_bounds__(256) void embed_k(
    const int* __restrict__ idx, const s16* __restrict__ emb, s16* __restrict__ x)
{
    int gid = blockIdx.x * 256 + threadIdx.x;
    int r = gid >> 6, cc = (gid & 63) * 8;
    int t = r >> 4, b = r & 15;
    int id = idx[b * 256 + t];
    *(bf16x8*)(x + (size_t)r * 512 + cc) = *(const bf16x8*)(emb + (size_t)id * 512 + cc);
}

// ---------------------------------------------------------------------------
// mel_shifted[(t*16+b)*80 + m] = (t==0) ? 0 : mel[b][t-1][m]  (f32 -> bf16)
// ---------------------------------------------------------------------------
__global__ __launch_bounds__(256) void melshift_k(
    const float* __restrict__ mel, s16* __restrict__ ms)
{
    int gid = blockIdx.x * 256 + threadIdx.x;
    if (gid >= 6400 * 20) return;
    int r = gid / 20, cc = (gid % 20) * 4;
    int t = r >> 4, b = r & 15;
    s16x4 o = {0, 0, 0, 0};
    if (t > 0) {
        float4 v = *(const float4*)(mel + ((size_t)b * 400 + (t - 1)) * 80 + cc);
        o = (s16x4){ f2b(v.x), f2b(v.y), f2b(v.z), f2b(v.w) };
    }
    *(s16x4*)(ms + (size_t)r * 80 + cc) = o;
}

// ---------------------------------------------------------------------------
// Persistent LSTM, 8 blocks per direction (grid = 8*ndir).
// dir = blk>>3, bb = blk&7. Block owns hidden units [bb*64, bb*64+64):
// wave w owns units [bb*64 + w*16, +16) for ALL FOUR gates — the MFMA C
// layout (col=unit, row=batch) gives each lane all 4 gates of its
// (batch,unit) cells, so the elementwise runs fully in-register.
//
// Exchange: UNIT-MAJOR tagged words (word = u*16 + beta, tag (step+1)<<16).
// Publish: TWO 64-bit relaxed agent atomic stores per lane (proven fast).
// Poll: s_sleep 16 back-off (publishes ack during sleep; skips hopeless
// early rounds), then 7x global_load_dwordx4 sc1, single vmcnt(0)/round,
// combined detection+data. h LDS parity double-buffered -> ONE
// __syncthreads/step. xg prefetched one step ahead (rotate).
// Race-freedom: published h depends (via MFMA over full K) on every polled
// word of the step, so publishes cannot pass the read phase.
// ---------------------------------------------------------------------------
__global__ __launch_bounds__(256, 1) void lstm_pers_k(
    const s16* __restrict__ Whh0, const s16* __restrict__ Whh1,
    const s16* __restrict__ xg0,  const s16* __restrict__ xg1,
    int rev0, int rev1, int T,
    unsigned* hxch, s16* hs, int hs_ld, int coff0, int coff1)
{
    int dir = blockIdx.x >> 3;
    int bb  = blockIdx.x & 7;
    int j0  = bb * 64;
    const s16* Whh = dir ? Whh1 : Whh0;
    const s16* xg  = dir ? xg1  : xg0;
    int rev        = dir ? rev1 : rev0;
    int coff       = dir ? coff1 : coff0;
    unsigned* hx   = hxch + (size_t)dir * 2 * 8192;

    int tid = threadIdx.x;
    int w = tid >> 6, l = tid & 63;
    int lr = l & 15, lk = l >> 4;

    // double-buffered swizzled h: byte = row*1024 + ((col*2)^((row&7)<<4))
    __shared__ s16 h_lds[2][16 * 512];

    int u  = j0 + w * 16 + lr;   // hidden unit this lane owns
    int b0 = lk * 4;             // first of the 4 batch rows this lane owns

    float cv[4] = {0.f, 0.f, 0.f, 0.f};

    // preload Whh fragments: wf[g][kk] = Whh[g*512 + u][kk*32 + lk*8 ..+8]
    bf16x8 wf[4][16];
    #pragma unroll
    for (int g = 0; g < 4; g++) {
        const s16* wr = Whh + (size_t)(g * 512 + u) * 512;
        #pragma unroll
        for (int kk = 0; kk < 16; kk++)
            wf[g][kk] = *(const bf16x8*)(wr + kk * 32 + lk * 8);
    }

    // h(0) = 0: self-stage own region of parity-0 buffer
    {
        char* lb0 = (char*)&h_lds[0][0];
        #pragma unroll
        for (int r = 0; r < 4; r++) {
            int row = b0 + r;
            *(s16*)(lb0 + row * 1024 + ((u * 2) ^ ((row & 7) << 4))) = 0;
        }
    }

    // prologue: xg for step 0
    s16 xv[4][4];
    {
        int t0 = rev ? (T - 1) : 0;
        const s16* xb = xg + ((size_t)t0 * 16 + b0) * 2048 + u;
        #pragma unroll
        for (int r = 0; r < 4; r++)
            #pragma unroll
            for (int g = 0; g < 4; g++)
                xv[g][r] = xb[(size_t)r * 2048 + g * 512];
    }

    int bw = tid * 4;                         // word offset inside a stripe
    #define STRIPE(i) ((((i) >= bb) ? (i) + 1 : (i)) * 1024)

    #define PISSUE(X0,X1,X2,X3,X4,X5,X6)                                    \
        asm volatile(                                                       \
            "global_load_dwordx4 %0, %7, off sc1\n\t"                       \
            "global_load_dwordx4 %1, %8, off sc1\n\t"                       \
            "global_load_dwordx4 %2, %9, off sc1\n\t"                       \
            "global_load_dwordx4 %3, %10, off sc1\n\t"                      \
            "global_load_dwordx4 %4, %11, off sc1\n\t"                      \
            "global_load_dwordx4 %5, %12, off sc1\n\t"                      \
            "global_load_dwordx4 %6, %13, off sc1\n\t"                      \
            "s_waitcnt vmcnt(0)"                                            \
            : "=&v"(X0), "=&v"(X1), "=&v"(X2), "=&v"(X3),                   \
              "=&v"(X4), "=&v"(X5), "=&v"(X6)                               \
            : "v"(q0), "v"(q1), "v"(q2), "v"(q3), "v"(q4), "v"(q5), "v"(q6) \
            : "memory")

    #define TAGOK(X0,X1,X2,X3,X4,X5,X6)                                     \
        ((((X0[0]^tgw)|(X0[2]^tgw) | (X1[0]^tgw)|(X1[2]^tgw) |              \
           (X2[0]^tgw)|(X2[2]^tgw) | (X3[0]^tgw)|(X3[2]^tgw) |              \
           (X4[0]^tgw)|(X4[2]^tgw) | (X5[0]^tgw)|(X5[2]^tgw) |              \
           (X6[0]^tgw)|(X6[2]^tgw)) & 0xffff0000u) == 0u)

    for (int s = 0; s < T; s++) {
        int te = rev ? (T - 1 - s) : s;
        int p  = s & 1;
        const unsigned tgw = ((unsigned)s) << 16;

        // back-off: publishes of step s-1 ack during the sleep (off the
        // critical path) and ~2 hopeless poll rounds' traffic disappear.
        // Data never arrives < ~2400cy after our publish; sleep ends at
        // ~2200cy post-publish -> cannot overshoot. Pure timing hint.
        if (s > 0) asm volatile("s_sleep 16");

        // READ phase: combined detect+data poll
        const unsigned* rb = hx + (size_t)p * 8192;
        const unsigned* q0 = rb + STRIPE(0) + bw;
        const unsigned* q1 = rb + STRIPE(1) + bw;
        const unsigned* q2 = rb + STRIPE(2) + bw;
        const unsigned* q3 = rb + STRIPE(3) + bw;
        const unsigned* q4 = rb + STRIPE(4) + bw;
        const unsigned* q5 = rb + STRIPE(5) + bw;
        const unsigned* q6 = rb + STRIPE(6) + bw;
        u32x4 A0, A1, A2, A3, A4, A5, A6;
        do {
            PISSUE(A0, A1, A2, A3, A4, A5, A6);
        } while (!TAGOK(A0, A1, A2, A3, A4, A5, A6));

        // prefetch NEXT step's xg now — hides under stage+sync+MFMA+elem
        s16 xn[4][4];
        bool havenext = (s + 1) < T;
        if (havenext) {
            int tn = rev ? (T - 2 - s) : (s + 1);
            const s16* xb = xg + ((size_t)tn * 16 + b0) * 2048 + u;
            #pragma unroll
            for (int r = 0; r < 4; r++)
                #pragma unroll
                for (int g = 0; g < 4; g++)
                    xn[g][r] = xb[(size_t)r * 2048 + g * 512];
        }

        // stage foreign words into swizzled LDS (word g -> col=g>>4, row=g&15)
        {
            char* lb = (char*)&h_lds[p][0];
            int row0 = bw & 15;
            auto stg = [&](int gw, u32x4 vv) {
                int col2 = (gw >> 4) * 2;
                #pragma unroll
                for (int k2 = 0; k2 < 4; k2++) {
                    int row = row0 + k2;
                    *(s16*)(lb + row * 1024 + (col2 ^ ((row & 7) << 4))) =
                        (s16)(vv[k2] & 0xffffu);
                }
            };
            stg(STRIPE(0) + bw, A0); stg(STRIPE(1) + bw, A1);
            stg(STRIPE(2) + bw, A2); stg(STRIPE(3) + bw, A3);
            stg(STRIPE(4) + bw, A4); stg(STRIPE(5) + bw, A5);
            stg(STRIPE(6) + bw, A6);
        }
        __syncthreads();

        // MFMA phase: acc[g] = h @ Whh[g-slice]   (C: col=unit, row=batch)
        f32x4 acc[4];
        #pragma unroll
        for (int i = 0; i < 4; i++) acc[i] = (f32x4){0.f, 0.f, 0.f, 0.f};
        const char* lb = (const char*)&h_lds[p][0];
        #pragma unroll
        for (int kk = 0; kk < 16; kk++) {
            bf16x8 af = *(const bf16x8*)(lb + lr * 1024 +
                             (((kk * 32 + lk * 8) * 2) ^ ((lr & 7) << 4)));
            #pragma unroll
            for (int g = 0; g < 4; g++)
                acc[g] = __builtin_amdgcn_mfma_f32_16x16x32_bf16(af, wf[g][kk], acc[g], 0, 0, 0);
        }

        // elementwise fully in-register (gate order i,f,g,o)
        s16 h4[4];
        #pragma unroll
        for (int r = 0; r < 4; r++) {
            float i_ = sigm_f(acc[0][r] + b2f(xv[0][r]));
            float f_ = sigm_f(acc[1][r] + b2f(xv[1][r]));
            float g_ = tanh_f(acc[2][r] + b2f(xv[2][r]));
            float o_ = sigm_f(acc[3][r] + b2f(xv[3][r]));
            float cn = f_ * cv[r] + i_ * g_;
            cv[r] = cn;
            h4[r] = f2b(o_ * tanh_f(cn));
        }

        // WRITE phase: publish tagged words as TWO 64-bit agent atomic
        // stores (unit-major, lane-contiguous; proven cache bits)
        {
            unsigned ntag = ((unsigned)(s + 1)) << 16;
            unsigned long long tag2 =
                ((unsigned long long)ntag << 32) | (unsigned long long)ntag;
            unsigned long long w0 = tag2
                | ((unsigned long long)(unsigned short)h4[1] << 32)
                | (unsigned long long)(unsigned short)h4[0];
            unsigned long long w1 = tag2
                | ((unsigned long long)(unsigned short)h4[3] << 32)
                | (unsigned long long)(unsigned short)h4[2];
            unsigned* wb = hx + (size_t)((s + 1) & 1) * 8192;
            unsigned long long* dst = (unsigned long long*)(wb + (u * 16 + b0));
            __hip_atomic_store(dst,     w0, __ATOMIC_RELAXED, __HIP_MEMORY_SCOPE_AGENT);
            __hip_atomic_store(dst + 1, w1, __ATOMIC_RELAXED, __HIP_MEMORY_SCOPE_AGENT);
        }
        // self-stage own h into next-parity LDS (no global round trip)
        {
            char* nb = (char*)&h_lds[p ^ 1][0];
            #pragma unroll
            for (int r = 0; r < 4; r++) {
                int row = b0 + r;
                *(s16*)(nb + row * 1024 + ((u * 2) ^ ((row & 7) << 4))) = h4[r];
            }
        }
        // h history (plain stores, off critical path)
        #pragma unroll
        for (int r = 0; r < 4; r++)
            hs[((size_t)te * 16 + b0 + r) * hs_ld + coff + u] = h4[r];

        // rotate prefetched xg into place
        if (havenext) {
            #pragma unroll
            for (int g = 0; g < 4; g++)
                #pragma unroll
                for (int r = 0; r < 4; r++)
                    xv[g][r] = xn[g][r];
        }
    }
    #undef STRIPE
    #undef PISSUE
    #undef TAGOK
}

// ---------------------------------------------------------------------------
// Fused attention: one block per (16 q-rows, head, batch).
// ---------------------------------------------------------------------------
__global__ __launch_bounds__(256) void attn_k(
    const s16* __restrict__ Q, const s16* __restrict__ Kmat,
    const s16* __restrict__ V, s16* __restrict__ Ao)
{
    __shared__ float S[16][256];
    __shared__ s16  P[16][256];

    int tile = blockIdx.x, head = blockIdx.y, b = blockIdx.z;
    int tq0 = tile * 16;
    int tid = threadIdx.x;
    int w = tid >> 6, l = tid & 63;
    int lr = l & 15, lk = l >> 4;
    int hoff = head * 64;

    f32x4 sacc[4];
    #pragma unroll
    for (int i = 0; i < 4; i++) sacc[i] = (f32x4){0.f, 0.f, 0.f, 0.f};

    for (int kk = 0; kk < 64; kk += 32) {
        int kb = kk + lk * 8;
        bf16x8 qf = *(const bf16x8*)(Q + (size_t)((tq0 + lr) * 16 + b) * 512 + hoff + kb);
        #pragma unroll
        for (int nb = 0; nb < 4; nb++) {
            int tk = w * 64 + nb * 16 + lr;
            bf16x8 kf = *(const bf16x8*)(Kmat + (size_t)(tk * 16 + b) * 512 + hoff + kb);
            sacc[nb] = __builtin_amdgcn_mfma_f32_16x16x32_bf16(qf, kf, sacc[nb], 0, 0, 0);
        }
    }
    #pragma unroll
    for (int nb = 0; nb < 4; nb++)
        #pragma unroll
        for (int r = 0; r < 4; r++)
            S[lk * 4 + r][w * 64 + nb * 16 + lr] = sacc[nb][r] * 0.125f;
    __syncthreads();

    {
        int row = tid >> 4, sl = tid & 15;
        float m = -1e30f;
        #pragma unroll
        for (int ii = 0; ii < 16; ii++) m = fmaxf(m, S[row][sl + 16 * ii]);
        #pragma unroll
        for (int off = 1; off < 16; off <<= 1) m = fmaxf(m, __shfl_xor(m, off));
        float sum = 0.f;
        #pragma unroll
        for (int ii = 0; ii < 16; ii++) {
            float e = expf(S[row][sl + 16 * ii] - m);
            S[row][sl + 16 * ii] = e;
            sum += e;
        }
        #pragma unroll
        for (int off = 1; off < 16; off <<= 1) sum += __shfl_xor(sum, off);
        float inv = 1.f / sum;
        #pragma unroll
        for (int ii = 0; ii < 16; ii++)
            P[row][sl + 16 * ii] = f2b(S[row][sl + 16 * ii] * inv);
    }
    __syncthreads();

    f32x4 oacc = (f32x4){0.f, 0.f, 0.f, 0.f};
    for (int kk = 0; kk < 256; kk += 32) {
        int kb = kk + lk * 8;
        bf16x8 pf = *(const bf16x8*)(&P[lr][kb]);
        bf16x8 vf;
        #pragma unroll
        for (int jj = 0; jj < 8; jj++)
            vf[jj] = V[(size_t)((kb + jj) * 16 + b) * 512 + hoff + w * 16 + lr];
        oacc = __builtin_amdgcn_mfma_f32_16x16x32_bf16(pf, vf, oacc, 0, 0, 0);
    }
    #pragma unroll
    for (int r = 0; r < 4; r++)
        Ao[(size_t)((tq0 + lk * 4 + r) * 16 + b) * 512 + hoff + w * 16 + lr] = f2b(oacc[r]);
}

// ---------------------------------------------------------------------------
extern "C" void kernel_launch(void* const* d_in, const int* in_sizes, int n_in,
                              void* d_out, int out_size, void* d_ws, size_t ws_size,
                              hipStream_t stream)
{
    const int*   pidx = (const int*)d_in[0];
    const float* mel  = (const float*)d_in[1];
    const float* emb  = (const float*)d_in[2];
    const float* fWih = (const float*)d_in[3];
    const float* fWhh = (const float*)d_in[4];
    const float* fbih = (const float*)d_in[5];
    const float* fbhh = (const float*)d_in[6];
    const float* bWih = (const float*)d_in[7];
    const float* bWhh = (const float*)d_in[8];
    const float* bbih = (const float*)d_in[9];
    const float* bbhh = (const float*)d_in[10];
    const float* tpW  = (const float*)d_in[11];
    const float* tpb  = (const float*)d_in[12];
    const float* mpiW = (const float*)d_in[13];
    const float* mpib = (const float*)d_in[14];
    const float* aiw  = (const float*)d_in[15];
    const float* aib  = (const float*)d_in[16];
    const float* aow  = (const float*)d_in[17];
    const float* aob  = (const float*)d_in[18];
    const float* dWih = (const float*)d_in[19];
    const float* dWhh = (const float*)d_in[20];
    const float* dbih = (const float*)d_in[21];
    const float* dbhh = (const float*)d_in[22];
    const float* mpoW = (const float*)d_in[23];
    const float* mpob = (const float*)d_in[24];

    char* ws = (char*)d_ws;
    size_t off = 0;
    auto alloc = [&](size_t bytes) -> char* {
        char* p = ws + off;
        off = (off + bytes + 255) & ~(size_t)255;
        return p;
    };

    // ---- bf16 weight copies ----
    s16* emb_b  = (s16*)alloc((size_t)131072 * 2);
    s16* fWih_b = (s16*)alloc((size_t)1048576 * 2);
    s16* fWhh_b = (s16*)alloc((size_t)1048576 * 2);
    s16* bWih_b = (s16*)alloc((size_t)1048576 * 2);
    s16* bWhh_b = (s16*)alloc((size_t)1048576 * 2);
    s16* tpW_b  = (s16*)alloc((size_t)524288 * 2);
    s16* mpiW_b = (s16*)alloc((size_t)40960 * 2);
    s16* aiw_b  = (s16*)alloc((size_t)786432 * 2);
    s16* aow_b  = (s16*)alloc((size_t)262144 * 2);
    s16* dWih_b = (s16*)alloc((size_t)2097152 * 2);
    s16* dWhh_b = (s16*)alloc((size_t)1048576 * 2);
    s16* mpoW_b = (s16*)alloc((size_t)40960 * 2);

    // ---- activation buffers (aliased; stream order makes it safe) ----
    char* xgreg = alloc((size_t)4096 * 2048 * 2 * 2);
    s16* xgf    = (s16*)xgreg;
    s16* xgb    = (s16*)(xgreg + (size_t)4096 * 2048 * 2);
    s16* xgd    = (s16*)xgreg;                               // alias (after encoder)
    s16* dec_hs = (s16*)(xgreg + (size_t)6400 * 2048 * 2);   // alias tail

    char* xreg  = alloc((size_t)4096 * 512 * 2);
    s16* x      = (s16*)xreg;
    s16* mshift = (s16*)xreg;                                // alias

    char* ereg  = alloc((size_t)4096 * 1024 * 2);
    s16* enc_hs = (s16*)ereg;
    s16* attno  = (s16*)ereg;                                // alias

    s16* tenc   = (s16*)alloc((size_t)4096 * 512 * 2);
    s16* decin  = (s16*)alloc((size_t)6400 * 1024 * 2);
    s16* Qb     = (s16*)alloc((size_t)6400 * 512 * 2);
    s16* Kb     = (s16*)alloc((size_t)4096 * 512 * 2);
    s16* Vb     = (s16*)alloc((size_t)4096 * 512 * 2);

    // tagged h-exchange buffers: enc 2 dirs x 2 x 8192 u32, dec 2 x 8192 u32
    unsigned* hx_e = (unsigned*)alloc((size_t)2 * 2 * 8192 * 4);
    unsigned* hx_d = (unsigned*)alloc((size_t)2 * 8192 * 4);

    hipMemsetAsync(hx_e, 0, (size_t)2 * 2 * 8192 * 4, stream);
    hipMemsetAsync(hx_d, 0, (size_t)2 * 8192 * 4, stream);

    // ---- fused weight conversion (single launch) ----
    {
        CvtArgs ca;
        int boff = 0;
        int i = 0;
        auto addseg = [&](const float* s, s16* d, int n) {
            ca.seg[i].src = s; ca.seg[i].dst = d; ca.seg[i].n4 = n / 4;
            ca.blk_off[i] = boff;
            boff += (n / 4 + 255) / 256;
            i++;
        };
        addseg(emb,  emb_b,  131072);
        addseg(fWih, fWih_b, 1048576);
        addseg(fWhh, fWhh_b, 1048576);
        addseg(bWih, bWih_b, 1048576);
        addseg(bWhh, bWhh_b, 1048576);
        addseg(tpW,  tpW_b,  524288);
        addseg(mpiW, mpiW_b, 40960);
        addseg(aiw,  aiw_b,  786432);
        addseg(aow,  aow_b,  262144);
        addseg(dWih, dWih_b, 2097152);
        addseg(dWhh, dWhh_b, 1048576);
        addseg(mpoW, mpoW_b, 40960);
        cvt_all_k<<<boff, 256, 0, stream>>>(ca);
    }

    auto gemm = [&](const s16* A, int lda, const s16* W, int ldw,
                    const float* b1, const float* b2,
                    s16* C, float* Cf, int ldc, int M, int N, int K, int perm) {
        dim3 g((M + 127) / 128, (N + 127) / 128);
        gemm_k<<<g, 256, 0, stream>>>(A, lda, W, ldw, b1, b2, C, Cf, ldc, M, N, K, perm);
    };

    // 1) embedding
    embed_k<<<1024, 256, 0, stream>>>(pidx, emb_b, x);

    // 2) encoder xg precompute (both directions)
    gemm(x, 512, fWih_b, 512, fbih, fbhh, xgf, nullptr, 2048, 4096, 2048, 512, 0);
    gemm(x, 512, bWih_b, 512, bbih, bbhh, xgb, nullptr, 2048, 4096, 2048, 512, 0);

    // 3) persistent bidirectional encoder LSTM (16 blocks, data-flow sync)
    lstm_pers_k<<<16, 256, 0, stream>>>(
        fWhh_b, bWhh_b, xgf, xgb, 0, 1, 256,
        hx_e, enc_hs, 1024, 0, 512);

    // 4) text projection
    gemm(enc_hs, 1024, tpW_b, 1024, tpb, nullptr, tenc, nullptr, 512, 4096, 512, 1024, 0);

    // 5) mel shift + input projection into decin cols [0,512)
    melshift_k<<<500, 256, 0, stream>>>(mel, mshift);
    gemm(mshift, 80, mpiW_b, 80, mpib, nullptr, decin, nullptr, 1024, 6400, 512, 80, 0);

    // 6) attention projections
    gemm(decin, 1024, aiw_b,              512, aib,       nullptr, Qb, nullptr, 512, 6400, 512, 512, 0);
    gemm(tenc,  512,  aiw_b + 512 * 512,  512, aib + 512, nullptr, Kb, nullptr, 512, 4096, 512, 512, 0);
    gemm(tenc,  512,  aiw_b + 1024 * 512, 512, aib + 1024,nullptr, Vb, nullptr, 512, 4096, 512, 512, 0);

    // 7) fused attention
    attn_k<<<dim3(25, 8, 16), 256, 0, stream>>>(Qb, Kb, Vb, attno);

    // 8) attention out-proj into decin cols [512,1024)
    gemm(attno, 512, aow_b, 512, aob, nullptr, decin + 512, nullptr, 1024, 6400, 512, 512, 0);

    // 9) decoder xg precompute (reuses xg region)
    gemm(decin, 1024, dWih_b, 1024, dbih, dbhh, xgd, nullptr, 2048, 6400, 2048, 1024, 0);

    // 10) persistent decoder LSTM (8 blocks, data-flow sync)
    lstm_pers_k<<<8, 256, 0, stream>>>(
        dWhh_b, dWhh_b, xgd, xgd, 0, 0, 400,
        hx_d, dec_hs, 512, 0, 0);

    // 11) output projection (f32 out) with [B][Tmel][M] permuted store
    gemm(dec_hs, 512, mpoW_b, 512, mpob, nullptr, nullptr, (float*)d_out, 80, 6400, 80, 512, 400);
}

// Round 12
// 2070.296 us; speedup vs baseline: 1.0700x; 1.0700x over previous
//
#include <hip/hip_runtime.h>
#include <hip/hip_bf16.h>
#include <math.h>

// ---------------------------------------------------------------------------
// KokoroModel: LSTM encoder (bidir) -> cross-attn -> LSTM decoder.
// B=16, T_txt=256, T_mel=400, H=512, NH=8, HD=64, V=256, M=80.
// Float inputs/outputs are FLOAT32 on device; indices int32.
// Internal compute: bf16 MFMA with f32 accumulation.
// Activation matrices are stored row-major with row index r = t*16 + b.
//
// LSTM recurrences: persistent kernels, 8 blocks x 256 thr per direction;
// h exchanged through TAGGED words ((step<<16)|bf16), parity double-buffered.
// CONVERGED configuration (r0-r11). Closed axes, do not revisit:
//  - publish: __hip_atomic_store(...,AGENT) 2x u64      [ONLY proven-fast]
//  - poll:    inline-asm global_load_dwordx4 sc1 + vmcnt(0)  [ONLY proven]
//  - sc0 loads / volatile stores / asm sc1 stores: NOT visible (r2,r4 hang)
//  - never exit a poll loop with loads in flight (r5 NaN: VGPR reuse)
//  - sentinel indirection (r6 -53%), atomic-RMW publish (r7 -32%): regress
//  - weight preload wf[4][16] (~256 regs, unified VGPR/AGPR file) is
//    LOAD-BEARING: in-loop Whh loads can't be hoisted past the poll's
//    "memory" clobbers (r8, 4.6x regress); 512-thr blocks cap regs at 256
//    -> wf spills to scratch (r9, 2.7x regress, VGPR_Count 128).
//  - s_sleep back-off before polling: +10% (r11) — wake-up quantization
//    costs more than the skipped poll rounds; traffic unchanged.
// Step time ~2.5us = compute (~1200cy) + MALL publish-to-visible latency.
// This is a synchronization-latency floor, not a BW/compute roofline.
// ---------------------------------------------------------------------------

typedef short s16;
typedef __attribute__((ext_vector_type(8))) short bf16x8;
typedef __attribute__((ext_vector_type(4))) short s16x4;
typedef __attribute__((ext_vector_type(4))) float f32x4;
typedef __attribute__((ext_vector_type(4))) unsigned u32x4;

#define DEV static __device__ __forceinline__

DEV float b2f(s16 v) {
    unsigned u = ((unsigned)(unsigned short)v) << 16;
    return __builtin_bit_cast(float, u);
}
DEV s16 f2b(float f) {
    unsigned u = __builtin_bit_cast(unsigned, f);
    return (s16)((u + 0x7fffu + ((u >> 16) & 1u)) >> 16);
}

// fast device transcendentals (v_exp_f32 / v_rcp_f32); |err| ~1e-7, far
// below the bf16 quantization already present in this pipeline.
DEV float sigm_f(float x) {
    return __builtin_amdgcn_rcpf(1.0f + __builtin_amdgcn_exp2f(-1.4426950408889634f * x));
}
DEV float tanh_f(float x) {
    float e = __builtin_amdgcn_exp2f(2.8853900817779268f * x);
    return 1.0f - 2.0f * __builtin_amdgcn_rcpf(e + 1.0f);
}

static const bf16x8 BZERO = {0,0,0,0,0,0,0,0};

// ---------------------------------------------------------------------------
// Fused f32 -> bf16 conversion for all 12 weight tensors (one launch).
// ---------------------------------------------------------------------------
struct CvtSeg { const float* src; s16* dst; int n4; };
struct CvtArgs { CvtSeg seg[12]; int blk_off[12]; };

__global__ __launch_bounds__(256) void cvt_all_k(CvtArgs a)
{
    int blk = blockIdx.x;
    int si = 0;
    #pragma unroll
    for (int k = 1; k < 12; k++) si += (blk >= a.blk_off[k]) ? 1 : 0;
    int i = (blk - a.blk_off[si]) * 256 + threadIdx.x;
    if (i >= a.seg[si].n4) return;
    float4 v = ((const float4*)a.seg[si].src)[i];
    s16x4 o = { f2b(v.x), f2b(v.y), f2b(v.z), f2b(v.w) };
    *(s16x4*)(a.seg[si].dst + 4 * (size_t)i) = o;
}

// ---------------------------------------------------------------------------
// Generic GEMM: C[M][N] = A[M][K](bf16) @ W[N][K]^T + b1 + b2.
// Block: 256 thr = 4 waves in 2x2; block tile 128(M) x 128(N);
// wave tile 64x64 = 4x4 MFMA subtiles; per K-step: 8 loads -> 16 MFMA.
// ---------------------------------------------------------------------------
__global__ __launch_bounds__(256) void gemm_k(
    const s16* __restrict__ A, int lda,
    const s16* __restrict__ W, int ldw,
    const float* __restrict__ b1, const float* __restrict__ b2,
    s16* __restrict__ C, float* __restrict__ Cf, int ldc,
    int M, int N, int K, int perm_tmel)
{
    int tid = threadIdx.x;
    int w = tid >> 6, l = tid & 63;
    int lr = l & 15, lk = l >> 4;
    int m0 = blockIdx.x * 128 + (w >> 1) * 64;
    int n0 = blockIdx.y * 128 + (w & 1) * 64;

    f32x4 acc[4][4];
    #pragma unroll
    for (int i = 0; i < 4; i++)
        #pragma unroll
        for (int j = 0; j < 4; j++) acc[i][j] = (f32x4){0.f, 0.f, 0.f, 0.f};

    for (int kk = 0; kk < K; kk += 32) {
        int kb = kk + lk * 8;
        bool kok = (kb + 8) <= K;
        bf16x8 av[4], bv[4];
        #pragma unroll
        for (int mi = 0; mi < 4; mi++) {
            int arow = m0 + mi * 16 + lr;
            av[mi] = (arow < M && kok) ? *(const bf16x8*)(A + (size_t)arow * lda + kb) : BZERO;
        }
        #pragma unroll
        for (int ni = 0; ni < 4; ni++) {
            int wrow = n0 + ni * 16 + lr;
            bv[ni] = (wrow < N && kok) ? *(const bf16x8*)(W + (size_t)wrow * ldw + kb) : BZERO;
        }
        #pragma unroll
        for (int mi = 0; mi < 4; mi++)
            #pragma unroll
            for (int ni = 0; ni < 4; ni++)
                acc[mi][ni] = __builtin_amdgcn_mfma_f32_16x16x32_bf16(av[mi], bv[ni], acc[mi][ni], 0, 0, 0);
    }

    #pragma unroll
    for (int ni = 0; ni < 4; ni++) {
        int col = n0 + ni * 16 + lr;
        if (col >= N) continue;
        float bias = 0.f;
        if (b1) bias += b1[col];
        if (b2) bias += b2[col];
        #pragma unroll
        for (int mi = 0; mi < 4; mi++) {
            #pragma unroll
            for (int r = 0; r < 4; r++) {
                int row = m0 + mi * 16 + lk * 4 + r;
                if (row >= M) continue;
                float v = acc[mi][ni][r] + bias;
                size_t oidx;
                if (perm_tmel) {
                    int bb = row & 15, t = row >> 4;
                    oidx = ((size_t)bb * perm_tmel + t) * ldc + col;
                } else {
                    oidx = (size_t)row * ldc + col;
                }
                if (Cf) Cf[oidx] = v;
                else    C[oidx] = f2b(v);
            }
        }
    }
}

// ---------------------------------------------------------------------------
// Embedding: x[(t*16+b)*512 + h] = emb_b[idx[b][t]*512 + h]  (bf16 gather)
// ---------------------------------------------------------------------------
__global__ __launch_bounds__(256) void embed_k(
    const int* __restrict__ idx, const s16* __restrict__ emb, s16* __restrict__ x)
{
    int gid = blockIdx.x * 256 + threadIdx.x;
    int r = gid >> 6, cc = (gid & 63) * 8;
    int t = r >> 4, b = r & 15;
    int id = idx[b * 256 + t];
    *(bf16x8*)(x + (size_t)r * 512 + cc) = *(const bf16x8*)(emb + (size_t)id * 512 + cc);
}

// ---------------------------------------------------------------------------
// mel_shifted[(t*16+b)*80 + m] = (t==0) ? 0 : mel[b][t-1][m]  (f32 -> bf16)
// ---------------------------------------------------------------------------
__global__ __launch_bounds__(256) void melshift_k(
    const float* __restrict__ mel, s16* __restrict__ ms)
{
    int gid = blockIdx.x * 256 + threadIdx.x;
    if (gid >= 6400 * 20) return;
    int r = gid / 20, cc = (gid % 20) * 4;
    int t = r >> 4, b = r & 15;
    s16x4 o = {0, 0, 0, 0};
    if (t > 0) {
        float4 v = *(const float4*)(mel + ((size_t)b * 400 + (t - 1)) * 80 + cc);
        o = (s16x4){ f2b(v.x), f2b(v.y), f2b(v.z), f2b(v.w) };
    }
    *(s16x4*)(ms + (size_t)r * 80 + cc) = o;
}

// ---------------------------------------------------------------------------
// Persistent LSTM, 8 blocks per direction (grid = 8*ndir).
// dir = blk>>3, bb = blk&7. Block owns hidden units [bb*64, bb*64+64):
// wave w owns units [bb*64 + w*16, +16) for ALL FOUR gates — the MFMA C
// layout (col=unit, row=batch) gives each lane all 4 gates of its
// (batch,unit) cells, so the elementwise runs fully in-register.
//
// Exchange: UNIT-MAJOR tagged words (word = u*16 + beta, tag (step+1)<<16).
// Publish: TWO 64-bit relaxed agent atomic stores per lane (proven fast).
// Poll: 7x global_load_dwordx4 sc1, single vmcnt(0)/round, combined
// detection+data. h LDS parity double-buffered -> ONE __syncthreads/step.
// xg prefetched one step ahead (rotate). Race-freedom: published h depends
// (via MFMA over full K) on every polled word of the step, so publishes
// cannot pass the read phase.
// ---------------------------------------------------------------------------
__global__ __launch_bounds__(256, 1) void lstm_pers_k(
    const s16* __restrict__ Whh0, const s16* __restrict__ Whh1,
    const s16* __restrict__ xg0,  const s16* __restrict__ xg1,
    int rev0, int rev1, int T,
    unsigned* hxch, s16* hs, int hs_ld, int coff0, int coff1)
{
    int dir = blockIdx.x >> 3;
    int bb  = blockIdx.x & 7;
    int j0  = bb * 64;
    const s16* Whh = dir ? Whh1 : Whh0;
    const s16* xg  = dir ? xg1  : xg0;
    int rev        = dir ? rev1 : rev0;
    int coff       = dir ? coff1 : coff0;
    unsigned* hx   = hxch + (size_t)dir * 2 * 8192;

    int tid = threadIdx.x;
    int w = tid >> 6, l = tid & 63;
    int lr = l & 15, lk = l >> 4;

    // double-buffered swizzled h: byte = row*1024 + ((col*2)^((row&7)<<4))
    __shared__ s16 h_lds[2][16 * 512];

    int u  = j0 + w * 16 + lr;   // hidden unit this lane owns
    int b0 = lk * 4;             // first of the 4 batch rows this lane owns

    float cv[4] = {0.f, 0.f, 0.f, 0.f};

    // preload Whh fragments: wf[g][kk] = Whh[g*512 + u][kk*32 + lk*8 ..+8]
    bf16x8 wf[4][16];
    #pragma unroll
    for (int g = 0; g < 4; g++) {
        const s16* wr = Whh + (size_t)(g * 512 + u) * 512;
        #pragma unroll
        for (int kk = 0; kk < 16; kk++)
            wf[g][kk] = *(const bf16x8*)(wr + kk * 32 + lk * 8);
    }

    // h(0) = 0: self-stage own region of parity-0 buffer
    {
        char* lb0 = (char*)&h_lds[0][0];
        #pragma unroll
        for (int r = 0; r < 4; r++) {
            int row = b0 + r;
            *(s16*)(lb0 + row * 1024 + ((u * 2) ^ ((row & 7) << 4))) = 0;
        }
    }

    // prologue: xg for step 0
    s16 xv[4][4];
    {
        int t0 = rev ? (T - 1) : 0;
        const s16* xb = xg + ((size_t)t0 * 16 + b0) * 2048 + u;
        #pragma unroll
        for (int r = 0; r < 4; r++)
            #pragma unroll
            for (int g = 0; g < 4; g++)
                xv[g][r] = xb[(size_t)r * 2048 + g * 512];
    }

    int bw = tid * 4;                         // word offset inside a stripe
    #define STRIPE(i) ((((i) >= bb) ? (i) + 1 : (i)) * 1024)

    #define PISSUE(X0,X1,X2,X3,X4,X5,X6)                                    \
        asm volatile(                                                       \
            "global_load_dwordx4 %0, %7, off sc1\n\t"                       \
            "global_load_dwordx4 %1, %8, off sc1\n\t"                       \
            "global_load_dwordx4 %2, %9, off sc1\n\t"                       \
            "global_load_dwordx4 %3, %10, off sc1\n\t"                      \
            "global_load_dwordx4 %4, %11, off sc1\n\t"                      \
            "global_load_dwordx4 %5, %12, off sc1\n\t"                      \
            "global_load_dwordx4 %6, %13, off sc1\n\t"                      \
            "s_waitcnt vmcnt(0)"                                            \
            : "=&v"(X0), "=&v"(X1), "=&v"(X2), "=&v"(X3),                   \
              "=&v"(X4), "=&v"(X5), "=&v"(X6)                               \
            : "v"(q0), "v"(q1), "v"(q2), "v"(q3), "v"(q4), "v"(q5), "v"(q6) \
            : "memory")

    #define TAGOK(X0,X1,X2,X3,X4,X5,X6)                                     \
        ((((X0[0]^tgw)|(X0[2]^tgw) | (X1[0]^tgw)|(X1[2]^tgw) |              \
           (X2[0]^tgw)|(X2[2]^tgw) | (X3[0]^tgw)|(X3[2]^tgw) |              \
           (X4[0]^tgw)|(X4[2]^tgw) | (X5[0]^tgw)|(X5[2]^tgw) |              \
           (X6[0]^tgw)|(X6[2]^tgw)) & 0xffff0000u) == 0u)

    for (int s = 0; s < T; s++) {
        int te = rev ? (T - 1 - s) : s;
        int p  = s & 1;
        const unsigned tgw = ((unsigned)s) << 16;

        // READ phase: combined detect+data poll
        const unsigned* rb = hx + (size_t)p * 8192;
        const unsigned* q0 = rb + STRIPE(0) + bw;
        const unsigned* q1 = rb + STRIPE(1) + bw;
        const unsigned* q2 = rb + STRIPE(2) + bw;
        const unsigned* q3 = rb + STRIPE(3) + bw;
        const unsigned* q4 = rb + STRIPE(4) + bw;
        const unsigned* q5 = rb + STRIPE(5) + bw;
        const unsigned* q6 = rb + STRIPE(6) + bw;
        u32x4 A0, A1, A2, A3, A4, A5, A6;
        do {
            PISSUE(A0, A1, A2, A3, A4, A5, A6);
        } while (!TAGOK(A0, A1, A2, A3, A4, A5, A6));

        // prefetch NEXT step's xg now — hides under stage+sync+MFMA+elem
        s16 xn[4][4];
        bool havenext = (s + 1) < T;
        if (havenext) {
            int tn = rev ? (T - 2 - s) : (s + 1);
            const s16* xb = xg + ((size_t)tn * 16 + b0) * 2048 + u;
            #pragma unroll
            for (int r = 0; r < 4; r++)
                #pragma unroll
                for (int g = 0; g < 4; g++)
                    xn[g][r] = xb[(size_t)r * 2048 + g * 512];
        }

        // stage foreign words into swizzled LDS (word g -> col=g>>4, row=g&15)
        {
            char* lb = (char*)&h_lds[p][0];
            int row0 = bw & 15;
            auto stg = [&](int gw, u32x4 vv) {
                int col2 = (gw >> 4) * 2;
                #pragma unroll
                for (int k2 = 0; k2 < 4; k2++) {
                    int row = row0 + k2;
                    *(s16*)(lb + row * 1024 + (col2 ^ ((row & 7) << 4))) =
                        (s16)(vv[k2] & 0xffffu);
                }
            };
            stg(STRIPE(0) + bw, A0); stg(STRIPE(1) + bw, A1);
            stg(STRIPE(2) + bw, A2); stg(STRIPE(3) + bw, A3);
            stg(STRIPE(4) + bw, A4); stg(STRIPE(5) + bw, A5);
            stg(STRIPE(6) + bw, A6);
        }
        __syncthreads();

        // MFMA phase: acc[g] = h @ Whh[g-slice]   (C: col=unit, row=batch)
        f32x4 acc[4];
        #pragma unroll
        for (int i = 0; i < 4; i++) acc[i] = (f32x4){0.f, 0.f, 0.f, 0.f};
        const char* lb = (const char*)&h_lds[p][0];
        #pragma unroll
        for (int kk = 0; kk < 16; kk++) {
            bf16x8 af = *(const bf16x8*)(lb + lr * 1024 +
                             (((kk * 32 + lk * 8) * 2) ^ ((lr & 7) << 4)));
            #pragma unroll
            for (int g = 0; g < 4; g++)
                acc[g] = __builtin_amdgcn_mfma_f32_16x16x32_bf16(af, wf[g][kk], acc[g], 0, 0, 0);
        }

        // elementwise fully in-register (gate order i,f,g,o)
        s16 h4[4];
        #pragma unroll
        for (int r = 0; r < 4; r++) {
            float i_ = sigm_f(acc[0][r] + b2f(xv[0][r]));
            float f_ = sigm_f(acc[1][r] + b2f(xv[1][r]));
            float g_ = tanh_f(acc[2][r] + b2f(xv[2][r]));
            float o_ = sigm_f(acc[3][r] + b2f(xv[3][r]));
            float cn = f_ * cv[r] + i_ * g_;
            cv[r] = cn;
            h4[r] = f2b(o_ * tanh_f(cn));
        }

        // WRITE phase: publish tagged words as TWO 64-bit agent atomic
        // stores (unit-major, lane-contiguous; proven cache bits)
        {
            unsigned ntag = ((unsigned)(s + 1)) << 16;
            unsigned long long tag2 =
                ((unsigned long long)ntag << 32) | (unsigned long long)ntag;
            unsigned long long w0 = tag2
                | ((unsigned long long)(unsigned short)h4[1] << 32)
                | (unsigned long long)(unsigned short)h4[0];
            unsigned long long w1 = tag2
                | ((unsigned long long)(unsigned short)h4[3] << 32)
                | (unsigned long long)(unsigned short)h4[2];
            unsigned* wb = hx + (size_t)((s + 1) & 1) * 8192;
            unsigned long long* dst = (unsigned long long*)(wb + (u * 16 + b0));
            __hip_atomic_store(dst,     w0, __ATOMIC_RELAXED, __HIP_MEMORY_SCOPE_AGENT);
            __hip_atomic_store(dst + 1, w1, __ATOMIC_RELAXED, __HIP_MEMORY_SCOPE_AGENT);
        }
        // self-stage own h into next-parity LDS (no global round trip)
        {
            char* nb = (char*)&h_lds[p ^ 1][0];
            #pragma unroll
            for (int r = 0; r < 4; r++) {
                int row = b0 + r;
                *(s16*)(nb + row * 1024 + ((u * 2) ^ ((row & 7) << 4))) = h4[r];
            }
        }
        // h history (plain stores, off critical path)
        #pragma unroll
        for (int r = 0; r < 4; r++)
            hs[((size_t)te * 16 + b0 + r) * hs_ld + coff + u] = h4[r];

        // rotate prefetched xg into place
        if (havenext) {
            #pragma unroll
            for (int g = 0; g < 4; g++)
                #pragma unroll
                for (int r = 0; r < 4; r++)
                    xv[g][r] = xn[g][r];
        }
    }
    #undef STRIPE
    #undef PISSUE
    #undef TAGOK
}

// ---------------------------------------------------------------------------
// Fused attention: one block per (16 q-rows, head, batch).
// ---------------------------------------------------------------------------
__global__ __launch_bounds__(256) void attn_k(
    const s16* __restrict__ Q, const s16* __restrict__ Kmat,
    const s16* __restrict__ V, s16* __restrict__ Ao)
{
    __shared__ float S[16][256];
    __shared__ s16  P[16][256];

    int tile = blockIdx.x, head = blockIdx.y, b = blockIdx.z;
    int tq0 = tile * 16;
    int tid = threadIdx.x;
    int w = tid >> 6, l = tid & 63;
    int lr = l & 15, lk = l >> 4;
    int hoff = head * 64;

    f32x4 sacc[4];
    #pragma unroll
    for (int i = 0; i < 4; i++) sacc[i] = (f32x4){0.f, 0.f, 0.f, 0.f};

    for (int kk = 0; kk < 64; kk += 32) {
        int kb = kk + lk * 8;
        bf16x8 qf = *(const bf16x8*)(Q + (size_t)((tq0 + lr) * 16 + b) * 512 + hoff + kb);
        #pragma unroll
        for (int nb = 0; nb < 4; nb++) {
            int tk = w * 64 + nb * 16 + lr;
            bf16x8 kf = *(const bf16x8*)(Kmat + (size_t)(tk * 16 + b) * 512 + hoff + kb);
            sacc[nb] = __builtin_amdgcn_mfma_f32_16x16x32_bf16(qf, kf, sacc[nb], 0, 0, 0);
        }
    }
    #pragma unroll
    for (int nb = 0; nb < 4; nb++)
        #pragma unroll
        for (int r = 0; r < 4; r++)
            S[lk * 4 + r][w * 64 + nb * 16 + lr] = sacc[nb][r] * 0.125f;
    __syncthreads();

    {
        int row = tid >> 4, sl = tid & 15;
        float m = -1e30f;
        #pragma unroll
        for (int ii = 0; ii < 16; ii++) m = fmaxf(m, S[row][sl + 16 * ii]);
        #pragma unroll
        for (int off = 1; off < 16; off <<= 1) m = fmaxf(m, __shfl_xor(m, off));
        float sum = 0.f;
        #pragma unroll
        for (int ii = 0; ii < 16; ii++) {
            float e = expf(S[row][sl + 16 * ii] - m);
            S[row][sl + 16 * ii] = e;
            sum += e;
        }
        #pragma unroll
        for (int off = 1; off < 16; off <<= 1) sum += __shfl_xor(sum, off);
        float inv = 1.f / sum;
        #pragma unroll
        for (int ii = 0; ii < 16; ii++)
            P[row][sl + 16 * ii] = f2b(S[row][sl + 16 * ii] * inv);
    }
    __syncthreads();

    f32x4 oacc = (f32x4){0.f, 0.f, 0.f, 0.f};
    for (int kk = 0; kk < 256; kk += 32) {
        int kb = kk + lk * 8;
        bf16x8 pf = *(const bf16x8*)(&P[lr][kb]);
        bf16x8 vf;
        #pragma unroll
        for (int jj = 0; jj < 8; jj++)
            vf[jj] = V[(size_t)((kb + jj) * 16 + b) * 512 + hoff + w * 16 + lr];
        oacc = __builtin_amdgcn_mfma_f32_16x16x32_bf16(pf, vf, oacc, 0, 0, 0);
    }
    #pragma unroll
    for (int r = 0; r < 4; r++)
        Ao[(size_t)((tq0 + lk * 4 + r) * 16 + b) * 512 + hoff + w * 16 + lr] = f2b(oacc[r]);
}

// ---------------------------------------------------------------------------
extern "C" void kernel_launch(void* const* d_in, const int* in_sizes, int n_in,
                              void* d_out, int out_size, void* d_ws, size_t ws_size,
                              hipStream_t stream)
{
    const int*   pidx = (const int*)d_in[0];
    const float* mel  = (const float*)d_in[1];
    const float* emb  = (const float*)d_in[2];
    const float* fWih = (const float*)d_in[3];
    const float* fWhh = (const float*)d_in[4];
    const float* fbih = (const float*)d_in[5];
    const float* fbhh = (const float*)d_in[6];
    const float* bWih = (const float*)d_in[7];
    const float* bWhh = (const float*)d_in[8];
    const float* bbih = (const float*)d_in[9];
    const float* bbhh = (const float*)d_in[10];
    const float* tpW  = (const float*)d_in[11];
    const float* tpb  = (const float*)d_in[12];
    const float* mpiW = (const float*)d_in[13];
    const float* mpib = (const float*)d_in[14];
    const float* aiw  = (const float*)d_in[15];
    const float* aib  = (const float*)d_in[16];
    const float* aow  = (const float*)d_in[17];
    const float* aob  = (const float*)d_in[18];
    const float* dWih = (const float*)d_in[19];
    const float* dWhh = (const float*)d_in[20];
    const float* dbih = (const float*)d_in[21];
    const float* dbhh = (const float*)d_in[22];
    const float* mpoW = (const float*)d_in[23];
    const float* mpob = (const float*)d_in[24];

    char* ws = (char*)d_ws;
    size_t off = 0;
    auto alloc = [&](size_t bytes) -> char* {
        char* p = ws + off;
        off = (off + bytes + 255) & ~(size_t)255;
        return p;
    };

    // ---- bf16 weight copies ----
    s16* emb_b  = (s16*)alloc((size_t)131072 * 2);
    s16* fWih_b = (s16*)alloc((size_t)1048576 * 2);
    s16* fWhh_b = (s16*)alloc((size_t)1048576 * 2);
    s16* bWih_b = (s16*)alloc((size_t)1048576 * 2);
    s16* bWhh_b = (s16*)alloc((size_t)1048576 * 2);
    s16* tpW_b  = (s16*)alloc((size_t)524288 * 2);
    s16* mpiW_b = (s16*)alloc((size_t)40960 * 2);
    s16* aiw_b  = (s16*)alloc((size_t)786432 * 2);
    s16* aow_b  = (s16*)alloc((size_t)262144 * 2);
    s16* dWih_b = (s16*)alloc((size_t)2097152 * 2);
    s16* dWhh_b = (s16*)alloc((size_t)1048576 * 2);
    s16* mpoW_b = (s16*)alloc((size_t)40960 * 2);

    // ---- activation buffers (aliased; stream order makes it safe) ----
    char* xgreg = alloc((size_t)4096 * 2048 * 2 * 2);
    s16* xgf    = (s16*)xgreg;
    s16* xgb    = (s16*)(xgreg + (size_t)4096 * 2048 * 2);
    s16* xgd    = (s16*)xgreg;                               // alias (after encoder)
    s16* dec_hs = (s16*)(xgreg + (size_t)6400 * 2048 * 2);   // alias tail

    char* xreg  = alloc((size_t)4096 * 512 * 2);
    s16* x      = (s16*)xreg;
    s16* mshift = (s16*)xreg;                                // alias

    char* ereg  = alloc((size_t)4096 * 1024 * 2);
    s16* enc_hs = (s16*)ereg;
    s16* attno  = (s16*)ereg;                                // alias

    s16* tenc   = (s16*)alloc((size_t)4096 * 512 * 2);
    s16* decin  = (s16*)alloc((size_t)6400 * 1024 * 2);
    s16* Qb     = (s16*)alloc((size_t)6400 * 512 * 2);
    s16* Kb     = (s16*)alloc((size_t)4096 * 512 * 2);
    s16* Vb     = (s16*)alloc((size_t)4096 * 512 * 2);

    // tagged h-exchange buffers: enc 2 dirs x 2 x 8192 u32, dec 2 x 8192 u32
    unsigned* hx_e = (unsigned*)alloc((size_t)2 * 2 * 8192 * 4);
    unsigned* hx_d = (unsigned*)alloc((size_t)2 * 8192 * 4);

    hipMemsetAsync(hx_e, 0, (size_t)2 * 2 * 8192 * 4, stream);
    hipMemsetAsync(hx_d, 0, (size_t)2 * 8192 * 4, stream);

    // ---- fused weight conversion (single launch) ----
    {
        CvtArgs ca;
        int boff = 0;
        int i = 0;
        auto addseg = [&](const float* s, s16* d, int n) {
            ca.seg[i].src = s; ca.seg[i].dst = d; ca.seg[i].n4 = n / 4;
            ca.blk_off[i] = boff;
            boff += (n / 4 + 255) / 256;
            i++;
        };
        addseg(emb,  emb_b,  131072);
        addseg(fWih, fWih_b, 1048576);
        addseg(fWhh, fWhh_b, 1048576);
        addseg(bWih, bWih_b, 1048576);
        addseg(bWhh, bWhh_b, 1048576);
        addseg(tpW,  tpW_b,  524288);
        addseg(mpiW, mpiW_b, 40960);
        addseg(aiw,  aiw_b,  786432);
        addseg(aow,  aow_b,  262144);
        addseg(dWih, dWih_b, 2097152);
        addseg(dWhh, dWhh_b, 1048576);
        addseg(mpoW, mpoW_b, 40960);
        cvt_all_k<<<boff, 256, 0, stream>>>(ca);
    }

    auto gemm = [&](const s16* A, int lda, const s16* W, int ldw,
                    const float* b1, const float* b2,
                    s16* C, float* Cf, int ldc, int M, int N, int K, int perm) {
        dim3 g((M + 127) / 128, (N + 127) / 128);
        gemm_k<<<g, 256, 0, stream>>>(A, lda, W, ldw, b1, b2, C, Cf, ldc, M, N, K, perm);
    };

    // 1) embedding
    embed_k<<<1024, 256, 0, stream>>>(pidx, emb_b, x);

    // 2) encoder xg precompute (both directions)
    gemm(x, 512, fWih_b, 512, fbih, fbhh, xgf, nullptr, 2048, 4096, 2048, 512, 0);
    gemm(x, 512, bWih_b, 512, bbih, bbhh, xgb, nullptr, 2048, 4096, 2048, 512, 0);

    // 3) persistent bidirectional encoder LSTM (16 blocks, data-flow sync)
    lstm_pers_k<<<16, 256, 0, stream>>>(
        fWhh_b, bWhh_b, xgf, xgb, 0, 1, 256,
        hx_e, enc_hs, 1024, 0, 512);

    // 4) text projection
    gemm(enc_hs, 1024, tpW_b, 1024, tpb, nullptr, tenc, nullptr, 512, 4096, 512, 1024, 0);

    // 5) mel shift + input projection into decin cols [0,512)
    melshift_k<<<500, 256, 0, stream>>>(mel, mshift);
    gemm(mshift, 80, mpiW_b, 80, mpib, nullptr, decin, nullptr, 1024, 6400, 512, 80, 0);

    // 6) attention projections
    gemm(decin, 1024, aiw_b,              512, aib,       nullptr, Qb, nullptr, 512, 6400, 512, 512, 0);
    gemm(tenc,  512,  aiw_b + 512 * 512,  512, aib + 512, nullptr, Kb, nullptr, 512, 4096, 512, 512, 0);
    gemm(tenc,  512,  aiw_b + 1024 * 512, 512, aib + 1024,nullptr, Vb, nullptr, 512, 4096, 512, 512, 0);

    // 7) fused attention
    attn_k<<<dim3(25, 8, 16), 256, 0, stream>>>(Qb, Kb, Vb, attno);

    // 8) attention out-proj into decin cols [512,1024)
    gemm(attno, 512, aow_b, 512, aob, nullptr, decin + 512, nullptr, 1024, 6400, 512, 512, 0);

    // 9) decoder xg precompute (reuses xg region)
    gemm(decin, 1024, dWih_b, 1024, dbih, dbhh, xgd, nullptr, 2048, 6400, 2048, 1024, 0);

    // 10) persistent decoder LSTM (8 blocks, data-flow sync)
    lstm_pers_k<<<8, 256, 0, stream>>>(
        dWhh_b, dWhh_b, xgd, xgd, 0, 0, 400,
        hx_d, dec_hs, 512, 0, 0);

    // 11) output projection (f32 out) with [B][Tmel][M] permuted store
    gemm(dec_hs, 512, mpoW_b, 512, mpob, nullptr, nullptr, (float*)d_out, 80, 6400, 80, 512, 400);
}